// Round 4
// baseline (224.050 us; speedup 1.0000x reference)
//
#include <hip/hip_runtime.h>

#define NB 64
#define NF 256
#define TIN 4096
#define TOUT 4096
#define BN_EPS 1e-5f

typedef float f32x4 __attribute__((ext_vector_type(4)));

// -------- helpers --------
__device__ __forceinline__ void waveReduce2(float& s, float& q) {
    #pragma unroll
    for (int off = 32; off > 0; off >>= 1) {
        s += __shfl_down(s, off, 64);
        q += __shfl_down(q, off, 64);
    }
}

// 4 consecutive output positions, gathering directly from the global row.
// Exact reference op order in fp32.
__device__ __forceinline__ f32x4 resample4(const float* __restrict__ row,
                                           int t0, float s, float st) {
    f32x4 r;
    #pragma unroll
    for (int j = 0; j < 4; ++j) {
        int t = t0 + j;
        float x = (2.0f * (float)t + 1.0f) * (1.0f / (float)TOUT) - 1.0f;
        float coord = s * x + st;
        float ix = ((coord + 1.0f) * (float)TIN - 1.0f) * 0.5f;
        float i0f = floorf(ix);
        float w = ix - i0f;
        int i0 = (int)i0f;
        int i1 = i0 + 1;
        float v0 = (i0 >= 0 && i0 < TIN) ? row[i0] : 0.0f;
        float v1 = (i1 >= 0 && i1 < TIN) ? row[i1] : 0.0f;
        r[j] = v0 * (1.0f - w) + v1 * w;
    }
    return r;
}

// -------- kernel 1: per-(b,f) row resample + partial sum/sumsq --------
__global__ __launch_bounds__(256) void k_resample_stats(
    const float* __restrict__ data,
    const float* __restrict__ translate,
    const float* __restrict__ scale,
    float2* __restrict__ partials)
{
    const int blk = blockIdx.x;
    const int f = blk & (NF - 1);
    const int b = blk >> 8;           // NF == 256
    const float* row = data + ((size_t)b * NF + f) * (size_t)TIN;

    __shared__ float2 wred[4];

    const float s = expf(scale[f] / 5.0f);
    const float st = s * translate[f];

    float sum = 0.0f, sq = 0.0f;
    #pragma unroll
    for (int k = 0; k < 4; ++k) {
        int t0 = (threadIdx.x + k * 256) * 4;
        f32x4 v = resample4(row, t0, s, st);
        sum += v.x + v.y + v.z + v.w;
        sq += v.x * v.x + v.y * v.y + v.z * v.z + v.w * v.w;
    }

    waveReduce2(sum, sq);
    const int lane = threadIdx.x & 63;
    const int wid = threadIdx.x >> 6;
    if (lane == 0) wred[wid] = make_float2(sum, sq);
    __syncthreads();
    if (threadIdx.x == 0) {
        float S = 0.0f, Q = 0.0f;
        #pragma unroll
        for (int i = 0; i < 4; ++i) { S += wred[i].x; Q += wred[i].y; }
        partials[blk] = make_float2(S, Q);
    }
}

// -------- kernel 2: stats-fused apply: recompute resample, BN affine --------
__global__ __launch_bounds__(256) void k_apply(
    const float* __restrict__ data,
    const float* __restrict__ translate,
    const float* __restrict__ scale,
    const float2* __restrict__ partials,
    const float* __restrict__ gamma,
    const float* __restrict__ beta,
    float* __restrict__ out)
{
    const int blk = blockIdx.x;
    const int f = blk & (NF - 1);
    const int b = blk >> 8;
    const size_t rowbase = ((size_t)b * NF + f) * (size_t)TIN;
    const float* row = data + rowbase;
    float* out_row = out + rowbase;     // TIN == TOUT

    __shared__ float2 s_ac;

    // wave 0: reduce the 64 batch partials for this feature -> (a, c)
    if (threadIdx.x < 64) {
        float2 p = partials[(size_t)threadIdx.x * NF + f];
        float S = p.x, Q = p.y;
        waveReduce2(S, Q);
        if (threadIdx.x == 0) {
            const float invN = 1.0f / (float)(NB * TOUT);
            float mean = S * invN;
            float var = Q * invN - mean * mean;
            float inv = 1.0f / sqrtf(var + BN_EPS);
            float a = gamma[f] * inv;
            s_ac = make_float2(a, beta[f] - mean * a);
        }
    }
    __syncthreads();

    const float s = expf(scale[f] / 5.0f);
    const float st = s * translate[f];
    const float a = s_ac.x;
    const float c = s_ac.y;

    #pragma unroll
    for (int k = 0; k < 4; ++k) {
        int t0 = (threadIdx.x + k * 256) * 4;
        f32x4 v = resample4(row, t0, s, st);
        v.x = v.x * a + c;
        v.y = v.y * a + c;
        v.z = v.z * a + c;
        v.w = v.w * a + c;
        __builtin_nontemporal_store(v, (f32x4*)(out_row + t0));
    }
}

extern "C" void kernel_launch(void* const* d_in, const int* in_sizes, int n_in,
                              void* d_out, int out_size, void* d_ws, size_t ws_size,
                              hipStream_t stream) {
    const float* data      = (const float*)d_in[0];
    const float* translate = (const float*)d_in[1];
    const float* scale     = (const float*)d_in[2];
    const float* gamma     = (const float*)d_in[3];
    const float* beta      = (const float*)d_in[4];
    float* out = (float*)d_out;

    float2* partials = (float2*)d_ws;            // NB*NF float2 = 128 KB

    k_resample_stats<<<NB * NF, 256, 0, stream>>>(data, translate, scale, partials);
    k_apply<<<NB * NF, 256, 0, stream>>>(data, translate, scale, partials,
                                         gamma, beta, out);
}

// Round 5
// 149.710 us; speedup vs baseline: 1.4966x; 1.4966x over previous
//
#include <hip/hip_runtime.h>

#define NB 64
#define NF 256
#define TIN 4096
#define TOUT 4096
#define BN_EPS 1e-5f

// Skewed LDS layout: word i lives at i + i/32 (one pad word per 32).
// Stride-4 gather (lane l reads ~4l+c) then hits banks (4l + l/8 + c)%32:
// all 32 banks across 32 lanes -> 2 lanes/bank = conflict-free (m136).
#define SKEW(i) ((i) + ((i) >> 5))
#define ROW_LDS (TIN + TIN / 32)   // 4224 floats = 16.9 KB

typedef float f32x4 __attribute__((ext_vector_type(4)));

// -------- helpers --------
__device__ __forceinline__ void waveReduce2(float& s, float& q) {
    #pragma unroll
    for (int off = 32; off > 0; off >>= 1) {
        s += __shfl_down(s, off, 64);
        q += __shfl_down(q, off, 64);
    }
}

__device__ __forceinline__ void stage_row(const float* __restrict__ row_g,
                                          float* __restrict__ row) {
    #pragma unroll
    for (int i = 0; i < TIN / 4 / 256; ++i) {
        int w = ((int)threadIdx.x + i * 256) * 4;       // w%32 in {0..28}
        f32x4 v = *(const f32x4*)(row_g + w);
        *(f32x4*)(row + SKEW(w)) = v;                   // same skew for all 4
    }
}

__device__ __forceinline__ void stage_row_nt(const float* __restrict__ row_g,
                                             float* __restrict__ row) {
    #pragma unroll
    for (int i = 0; i < TIN / 4 / 256; ++i) {
        int w = ((int)threadIdx.x + i * 256) * 4;
        f32x4 v = __builtin_nontemporal_load((const f32x4*)(row_g + w));
        *(f32x4*)(row + SKEW(w)) = v;
    }
}

// 4 consecutive output positions from the skewed LDS row.
// Exact reference op order in fp32.
__device__ __forceinline__ f32x4 resample4(const float* __restrict__ row,
                                           int t0, float s, float st) {
    f32x4 r;
    #pragma unroll
    for (int j = 0; j < 4; ++j) {
        int t = t0 + j;
        float x = (2.0f * (float)t + 1.0f) * (1.0f / (float)TOUT) - 1.0f;
        float coord = s * x + st;
        float ix = ((coord + 1.0f) * (float)TIN - 1.0f) * 0.5f;
        float i0f = floorf(ix);
        float w = ix - i0f;
        int i0 = (int)i0f;
        int i1 = i0 + 1;
        int i0c = min(max(i0, 0), TIN - 1);
        int i1c = min(max(i1, 0), TIN - 1);
        float v0 = row[SKEW(i0c)];
        float v1 = row[SKEW(i1c)];
        v0 = (i0 >= 0 && i0 < TIN) ? v0 : 0.0f;
        v1 = (i1 < TIN) ? v1 : 0.0f;          // i1 >= 0 always when i0 >= -1; i1<0 impossible if i0>=-? (i0=-2 => w? ) 
        v1 = (i1 >= 0) ? v1 : 0.0f;
        r[j] = v0 * (1.0f - w) + v1 * w;
    }
    return r;
}

// -------- kernel 1: per-(b,f) row resample + partial sum/sumsq --------
__global__ __launch_bounds__(256) void k_resample_stats(
    const float* __restrict__ data,
    const float* __restrict__ translate,
    const float* __restrict__ scale,
    float2* __restrict__ partials)
{
    const int blk = blockIdx.x;
    const int f = blk & (NF - 1);
    const int b = blk >> 8;           // NF == 256
    const float* row_g = data + ((size_t)b * NF + f) * (size_t)TIN;

    __shared__ float row[ROW_LDS];
    __shared__ float2 wred[4];

    stage_row(row_g, row);            // regular loads: allocate into L3
    __syncthreads();

    const float s = expf(scale[f] / 5.0f);
    const float st = s * translate[f];

    float sum = 0.0f, sq = 0.0f;
    #pragma unroll
    for (int k = 0; k < 4; ++k) {
        int t0 = (threadIdx.x + k * 256) * 4;
        f32x4 v = resample4(row, t0, s, st);
        sum += v.x + v.y + v.z + v.w;
        sq += v.x * v.x + v.y * v.y + v.z * v.z + v.w * v.w;
    }

    waveReduce2(sum, sq);
    const int lane = threadIdx.x & 63;
    const int wid = threadIdx.x >> 6;
    if (lane == 0) wred[wid] = make_float2(sum, sq);
    __syncthreads();
    if (threadIdx.x == 0) {
        float S = 0.0f, Q = 0.0f;
        #pragma unroll
        for (int i = 0; i < 4; ++i) { S += wred[i].x; Q += wred[i].y; }
        partials[blk] = make_float2(S, Q);
    }
}

// -------- kernel 2: stats-fused apply: recompute resample, BN affine --------
__global__ __launch_bounds__(256) void k_apply(
    const float* __restrict__ data,
    const float* __restrict__ translate,
    const float* __restrict__ scale,
    const float2* __restrict__ partials,
    const float* __restrict__ gamma,
    const float* __restrict__ beta,
    float* __restrict__ out)
{
    const int blk = blockIdx.x;
    const int f = blk & (NF - 1);
    const int b = blk >> 8;
    const size_t rowbase = ((size_t)b * NF + f) * (size_t)TIN;
    const float* row_g = data + rowbase;
    float* out_row = out + rowbase;     // TIN == TOUT

    __shared__ float row[ROW_LDS];
    __shared__ float2 s_ac;

    stage_row_nt(row_g, row);           // last touch of data: nt loads

    // wave 0: reduce the 64 batch partials for this feature -> (a, c)
    if (threadIdx.x < 64) {
        float2 p = partials[(size_t)threadIdx.x * NF + f];
        float S = p.x, Q = p.y;
        waveReduce2(S, Q);
        if (threadIdx.x == 0) {
            const float invN = 1.0f / (float)(NB * TOUT);
            float mean = S * invN;
            float var = Q * invN - mean * mean;
            float inv = 1.0f / sqrtf(var + BN_EPS);
            float a = gamma[f] * inv;
            s_ac = make_float2(a, beta[f] - mean * a);
        }
    }
    __syncthreads();

    const float s = expf(scale[f] / 5.0f);
    const float st = s * translate[f];
    const float a = s_ac.x;
    const float c = s_ac.y;

    #pragma unroll
    for (int k = 0; k < 4; ++k) {
        int t0 = (threadIdx.x + k * 256) * 4;
        f32x4 v = resample4(row, t0, s, st);
        v.x = v.x * a + c;
        v.y = v.y * a + c;
        v.z = v.z * a + c;
        v.w = v.w * a + c;
        __builtin_nontemporal_store(v, (f32x4*)(out_row + t0));
    }
}

extern "C" void kernel_launch(void* const* d_in, const int* in_sizes, int n_in,
                              void* d_out, int out_size, void* d_ws, size_t ws_size,
                              hipStream_t stream) {
    const float* data      = (const float*)d_in[0];
    const float* translate = (const float*)d_in[1];
    const float* scale     = (const float*)d_in[2];
    const float* gamma     = (const float*)d_in[3];
    const float* beta      = (const float*)d_in[4];
    float* out = (float*)d_out;

    float2* partials = (float2*)d_ws;            // NB*NF float2 = 128 KB

    k_resample_stats<<<NB * NF, 256, 0, stream>>>(data, translate, scale, partials);
    k_apply<<<NB * NF, 256, 0, stream>>>(data, translate, scale, partials,
                                         gamma, beta, out);
}

// Round 6
// 128.645 us; speedup vs baseline: 1.7416x; 1.1637x over previous
//
#include <hip/hip_runtime.h>

#define NB 64
#define NF 256
#define TIN 4096
#define TOUT 4096
#define BN_EPS 1e-5f

typedef float f32x4 __attribute__((ext_vector_type(4)));

// -------- helpers --------
__device__ __forceinline__ void waveReduce2(float& s, float& q) {
    #pragma unroll
    for (int off = 32; off > 0; off >>= 1) {
        s += __shfl_down(s, off, 64);
        q += __shfl_down(q, off, 64);
    }
}

// ix(t) = s*t + C  (closed form of the reference coordinate chain; bilinear
// interp is continuous in ix so few-ulp deviation is harmless vs 0.129 thr)
__device__ __forceinline__ f32x4 resample4(const float* __restrict__ row,
                                           int t0, float s, float C) {
    f32x4 r;
    const float tf = (float)t0;
    #pragma unroll
    for (int j = 0; j < 4; ++j) {
        float ix = fmaf(s, tf + (float)j, C);
        float i0f = floorf(ix);
        float w = ix - i0f;
        int i0 = (int)i0f;
        int i1 = i0 + 1;
        float v0 = (i0 >= 0 && i0 < TIN) ? row[i0] : 0.0f;
        float v1 = (i1 >= 0 && i1 < TIN) ? row[i1] : 0.0f;
        r[j] = fmaf(w, v1 - v0, v0);
    }
    return r;
}

__device__ __forceinline__ void stage_row(const float* __restrict__ row_g,
                                          float* __restrict__ row) {
    const f32x4* src4 = (const f32x4*)row_g;
    f32x4* dst4 = (f32x4*)row;
    #pragma unroll
    for (int i = 0; i < TIN / 4 / 256; ++i)
        dst4[threadIdx.x + i * 256] = src4[threadIdx.x + i * 256];
}

__device__ __forceinline__ float2 row_consts(const float* translate,
                                             const float* scale, int f) {
    float s = expf(scale[f] / 5.0f);
    float st = s * translate[f];
    // ix = ((s*x + st + 1)*TIN - 1)/2 with x = (2t+1)/TOUT - 1
    //    = s*t*(TIN/TOUT) + C
    float C = (s * (1.0f / (float)TOUT - 1.0f) + st + 1.0f) * (0.5f * (float)TIN)
              - 0.5f;
    return make_float2(s, C);   // TIN == TOUT so slope = s
}

// -------- kernel 1: per-(b,f) row resample + partial sum/sumsq --------
__global__ __launch_bounds__(256) void k_resample_stats(
    const float* __restrict__ data,
    const float* __restrict__ translate,
    const float* __restrict__ scale,
    float2* __restrict__ partials)
{
    const int blk = blockIdx.x;
    const int f = blk & (NF - 1);
    const int b = blk >> 8;           // NF == 256
    const float* row_g = data + ((size_t)b * NF + f) * (size_t)TIN;

    __shared__ float row[TIN];
    __shared__ float2 wred[4];

    stage_row(row_g, row);            // regular loads: allocate into L3
    __syncthreads();

    const float2 sc = row_consts(translate, scale, f);

    float sum = 0.0f, sq = 0.0f;
    #pragma unroll
    for (int k = 0; k < 4; ++k) {
        int t0 = (threadIdx.x + k * 256) * 4;
        f32x4 v = resample4(row, t0, sc.x, sc.y);
        sum += v.x + v.y + v.z + v.w;
        sq += v.x * v.x + v.y * v.y + v.z * v.z + v.w * v.w;
    }

    waveReduce2(sum, sq);
    const int lane = threadIdx.x & 63;
    const int wid = threadIdx.x >> 6;
    if (lane == 0) wred[wid] = make_float2(sum, sq);
    __syncthreads();
    if (threadIdx.x == 0) {
        float S = 0.0f, Q = 0.0f;
        #pragma unroll
        for (int i = 0; i < 4; ++i) { S += wred[i].x; Q += wred[i].y; }
        partials[blk] = make_float2(S, Q);
    }
}

// -------- kernel 2: stats-fused apply: recompute resample, BN affine --------
__global__ __launch_bounds__(256) void k_apply(
    const float* __restrict__ data,
    const float* __restrict__ translate,
    const float* __restrict__ scale,
    const float2* __restrict__ partials,
    const float* __restrict__ gamma,
    const float* __restrict__ beta,
    float* __restrict__ out)
{
    const int blk = blockIdx.x;
    const int f = blk & (NF - 1);
    const int b = blk >> 8;
    const size_t rowbase = ((size_t)b * NF + f) * (size_t)TIN;
    const float* row_g = data + rowbase;
    float* out_row = out + rowbase;     // TIN == TOUT

    __shared__ float row[TIN];
    __shared__ float2 s_ac;

    stage_row(row_g, row);              // REGULAR loads: keep data L3-resident

    // wave 0: reduce the 64 batch partials for this feature -> (a, c)
    if (threadIdx.x < 64) {
        float2 p = partials[(size_t)threadIdx.x * NF + f];
        float S = p.x, Q = p.y;
        waveReduce2(S, Q);
        if (threadIdx.x == 0) {
            const float invN = 1.0f / (float)(NB * TOUT);
            float mean = S * invN;
            float var = Q * invN - mean * mean;
            float inv = 1.0f / sqrtf(var + BN_EPS);
            float a = gamma[f] * inv;
            s_ac = make_float2(a, beta[f] - mean * a);
        }
    }
    __syncthreads();

    const float2 sc = row_consts(translate, scale, f);
    const float a = s_ac.x;
    const float c = s_ac.y;

    #pragma unroll
    for (int k = 0; k < 4; ++k) {
        int t0 = (threadIdx.x + k * 256) * 4;
        f32x4 v = resample4(row, t0, sc.x, sc.y);
        v.x = v.x * a + c;
        v.y = v.y * a + c;
        v.z = v.z * a + c;
        v.w = v.w * a + c;
        __builtin_nontemporal_store(v, (f32x4*)(out_row + t0));  // no-allocate
    }
}

extern "C" void kernel_launch(void* const* d_in, const int* in_sizes, int n_in,
                              void* d_out, int out_size, void* d_ws, size_t ws_size,
                              hipStream_t stream) {
    const float* data      = (const float*)d_in[0];
    const float* translate = (const float*)d_in[1];
    const float* scale     = (const float*)d_in[2];
    const float* gamma     = (const float*)d_in[3];
    const float* beta      = (const float*)d_in[4];
    float* out = (float*)d_out;

    float2* partials = (float2*)d_ws;            // NB*NF float2 = 128 KB

    k_resample_stats<<<NB * NF, 256, 0, stream>>>(data, translate, scale, partials);
    k_apply<<<NB * NF, 256, 0, stream>>>(data, translate, scale, partials,
                                         gamma, beta, out);
}